// Round 1
// baseline (188.258 us; speedup 1.0000x reference)
//
#include <hip/hip_runtime.h>
#include <math.h>

#define NN 16384

// One 64-lane wave per output row. 4 waves / 256-thread block.
// Row = 16384 floats = 4096 float4; 64 lanes -> 64 float4 iters/lane.
__global__ __launch_bounds__(256) void net_step_kernel(
    const float* __restrict__ rates,
    const float* __restrict__ noise,
    const float* __restrict__ W,
    const float* __restrict__ bias,
    const float* __restrict__ exp_dt_tau,
    const float* __restrict__ dt_tau,
    float* __restrict__ out)
{
    const int wave = (int)((blockIdx.x * blockDim.x + threadIdx.x) >> 6);
    const int lane = (int)(threadIdx.x & 63);
    if (wave >= NN) return;

    const float4* __restrict__ Wrow =
        reinterpret_cast<const float4*>(W + (size_t)wave * NN);
    const float4* __restrict__ r4 =
        reinterpret_cast<const float4*>(rates);

    float acc = 0.0f;
#pragma unroll 4
    for (int i = lane; i < NN / 4; i += 64) {
        float4 w = Wrow[i];
        float4 r = r4[i];
        acc += w.x * r.x + w.y * r.y + w.z * r.z + w.w * r.w;
    }

    // 64-lane butterfly reduction
#pragma unroll
    for (int off = 32; off > 0; off >>= 1)
        acc += __shfl_xor(acc, off);

    if (lane == 0) {
        float net = acc + bias[wave] + noise[wave];
        // THRESH * 0.5 * (1 + erf(net / sqrt(2)))
        float act = 7.5f * (1.0f + erff(net * 0.70710678f));
        out[wave] = rates[wave] * exp_dt_tau[wave] + dt_tau[wave] * act;
    }
}

extern "C" void kernel_launch(void* const* d_in, const int* in_sizes, int n_in,
                              void* d_out, int out_size, void* d_ws, size_t ws_size,
                              hipStream_t stream) {
    const float* rates      = (const float*)d_in[0];
    const float* noise      = (const float*)d_in[1];
    const float* W          = (const float*)d_in[2];
    const float* bias       = (const float*)d_in[3];
    const float* exp_dt_tau = (const float*)d_in[4];
    const float* dt_tau     = (const float*)d_in[5];
    float* out = (float*)d_out;

    // N waves -> N/4 blocks of 256 threads
    dim3 grid(NN / 4), block(256);
    hipLaunchKernelGGL(net_step_kernel, grid, block, 0, stream,
                       rates, noise, W, bias, exp_dt_tau, dt_tau, out);
}

// Round 3
// 164.795 us; speedup vs baseline: 1.1424x; 1.1424x over previous
//
#include <hip/hip_runtime.h>
#include <math.h>

#define NN 16384

typedef float f32x4 __attribute__((ext_vector_type(4)));

// One 64-lane wave per output row. 4 waves / 256-thread block.
// Row = 16384 floats = 4096 float4; 64 lanes -> 64 float4 iters/lane.
// R3: 4 independent accumulators (break FMA dep chain), full unroll,
//     nontemporal loads on the stream-once W (native clang vector type
//     required by __builtin_nontemporal_load) to preserve L2 for rates.
__global__ __launch_bounds__(256) void net_step_kernel(
    const float* __restrict__ rates,
    const float* __restrict__ noise,
    const float* __restrict__ W,
    const float* __restrict__ bias,
    const float* __restrict__ exp_dt_tau,
    const float* __restrict__ dt_tau,
    float* __restrict__ out)
{
    const int wave = (int)((blockIdx.x * blockDim.x + threadIdx.x) >> 6);
    const int lane = (int)(threadIdx.x & 63);
    if (wave >= NN) return;

    const f32x4* __restrict__ Wrow =
        reinterpret_cast<const f32x4*>(W + (size_t)wave * NN);
    const f32x4* __restrict__ r4 =
        reinterpret_cast<const f32x4*>(rates);

    float acc0 = 0.0f, acc1 = 0.0f, acc2 = 0.0f, acc3 = 0.0f;
#pragma unroll 8
    for (int j = 0; j < 64; j += 4) {
        const int i0 = lane + ((j + 0) << 6);
        const int i1 = lane + ((j + 1) << 6);
        const int i2 = lane + ((j + 2) << 6);
        const int i3 = lane + ((j + 3) << 6);
        f32x4 w0 = __builtin_nontemporal_load(Wrow + i0);
        f32x4 w1 = __builtin_nontemporal_load(Wrow + i1);
        f32x4 w2 = __builtin_nontemporal_load(Wrow + i2);
        f32x4 w3 = __builtin_nontemporal_load(Wrow + i3);
        f32x4 r0 = r4[i0];
        f32x4 r1 = r4[i1];
        f32x4 r2 = r4[i2];
        f32x4 r3 = r4[i3];
        acc0 += w0.x * r0.x + w0.y * r0.y + w0.z * r0.z + w0.w * r0.w;
        acc1 += w1.x * r1.x + w1.y * r1.y + w1.z * r1.z + w1.w * r1.w;
        acc2 += w2.x * r2.x + w2.y * r2.y + w2.z * r2.z + w2.w * r2.w;
        acc3 += w3.x * r3.x + w3.y * r3.y + w3.z * r3.z + w3.w * r3.w;
    }
    float acc = (acc0 + acc1) + (acc2 + acc3);

    // 64-lane butterfly reduction
#pragma unroll
    for (int off = 32; off > 0; off >>= 1)
        acc += __shfl_xor(acc, off);

    if (lane == 0) {
        float net = acc + bias[wave] + noise[wave];
        // THRESH * 0.5 * (1 + erf(net / sqrt(2)))
        float act = 7.5f * (1.0f + erff(net * 0.70710678f));
        out[wave] = rates[wave] * exp_dt_tau[wave] + dt_tau[wave] * act;
    }
}

extern "C" void kernel_launch(void* const* d_in, const int* in_sizes, int n_in,
                              void* d_out, int out_size, void* d_ws, size_t ws_size,
                              hipStream_t stream) {
    const float* rates      = (const float*)d_in[0];
    const float* noise      = (const float*)d_in[1];
    const float* W          = (const float*)d_in[2];
    const float* bias       = (const float*)d_in[3];
    const float* exp_dt_tau = (const float*)d_in[4];
    const float* dt_tau     = (const float*)d_in[5];
    float* out = (float*)d_out;

    // N waves -> N/4 blocks of 256 threads
    dim3 grid(NN / 4), block(256);
    hipLaunchKernelGGL(net_step_kernel, grid, block, 0, stream,
                       rates, noise, W, bias, exp_dt_tau, dt_tau, out);
}